// Round 6
// baseline (432.625 us; speedup 1.0000x reference)
//
#include <hip/hip_runtime.h>

#define NNODES 25600
#define DEG 16
#define BGRAPHS 8
#define NPG (NNODES / BGRAPHS)   // 3200
#define FDIM 7
#define HDIM 300
#define LDIM 100
#define HP 320                   // padded H
#define UVW 640                  // UV row width (U 0..319 | V 320..639)
#define NT1 20                   // GEMM1 N tiles
#define KS1 10                   // GEMM1 K steps
#define NT2 7                    // GEMM2 N tiles (112 cols, >=100 masked)
#define KS2 10                   // GEMM2 K steps
#define H0W 128                  // h0 fp16 padded width
#define SSTR 328                 // proj staging row stride (shorts)

typedef __attribute__((ext_vector_type(8))) _Float16 half8;
typedef __attribute__((ext_vector_type(2))) _Float16 half2v;
typedef __attribute__((ext_vector_type(4))) float floatx4;

__device__ __forceinline__ unsigned short f2h(float f) {   // fp32 -> fp16 bits (RNE)
    _Float16 h = (_Float16)f;
    return __builtin_bit_cast(unsigned short, h);
}

// packed fp32x2 -> fp16x2 (RTZ), re-typed to half2v
__device__ __forceinline__ half2v pkrtz(float a, float b) {
    return __builtin_bit_cast(half2v, __builtin_amdgcn_cvt_pkrtz(a, b));
}

union UV4H { uint4 v; half2v h[4]; };

// ---------------------------------------------------------------------------
// B-fragment packing: out[((nt*KS+ks)*64+lane)*8+j] = W[k][n]  (fp16 bits)
// ---------------------------------------------------------------------------
__device__ __forceinline__ unsigned short packB(const float* W, int Kreal, int Nreal,
                                                int KS, int rel)
{
    int j = rel & 7, lane = (rel >> 3) & 63, rem = rel >> 9;
    int ks = rem % KS, nt = rem / KS;
    int k = ks * 32 + ((lane >> 4) << 3) + j;
    int n = nt * 16 + (lane & 15);
    float v = (k < Kreal && n < Nreal) ? W[k * Nreal + n] : 0.f;
    return f2h(v);
}

// proj effective weights Weff[k][n], n<320 = U part (W1a - W1b), n>=320 = V part (W1b)
__device__ __forceinline__ unsigned short packProjW(const float* W1, int Ksub,
                                                    int KS, int rel)
{
    int j = rel & 7, lane = (rel >> 3) & 63, rem = rel >> 9;
    int ks = rem % KS, nt = rem / KS;
    int k = ks * 32 + ((lane >> 4) << 3) + j;
    int n = nt * 16 + (lane & 15);
    float v = 0.f;
    if (k < Ksub) {
        if (n < HP) { if (n < HDIM) v = W1[k * HDIM + n] - W1[(k + Ksub) * HDIM + n]; }
        else { int m = n - HP; if (m < HDIM) v = W1[(k + Ksub) * HDIM + m]; }
    }
    return f2h(v);
}

#define S0 102400   // PB2_0
#define S1 102400   // PB2_1
#define S2 35840    // PB3_0
#define S3 35840    // PB3_1
#define S4 81920    // PW1 (40 nt x 4 ks)
#define S5 20480    // PW0 (40 nt x 1 ks)
#define S6 1920     // biases
#define S7 40000    // part zero (200 slices x 200 floats)
#define PACK_TOTAL (S0+S1+S2+S3+S4+S5+S6+S7)

__global__ __launch_bounds__(256) void pack_all_kernel(
    const float* __restrict__ l0_W1, const float* __restrict__ l0_b1,
    const float* __restrict__ l0_W2, const float* __restrict__ l0_b2,
    const float* __restrict__ l0_W3,
    const float* __restrict__ l1_W1, const float* __restrict__ l1_b1,
    const float* __restrict__ l1_W2, const float* __restrict__ l1_b2,
    const float* __restrict__ l1_W3,
    unsigned short* __restrict__ PB2_0, unsigned short* __restrict__ PB2_1,
    unsigned short* __restrict__ PB3_0, unsigned short* __restrict__ PB3_1,
    unsigned short* __restrict__ PW1,  unsigned short* __restrict__ PW0,
    float* __restrict__ b2p_0, float* __restrict__ b2p_1,
    float* __restrict__ bp1,   float* __restrict__ bp0,
    float* __restrict__ part)
{
    int idx = blockIdx.x * 256 + threadIdx.x;
    if (idx >= PACK_TOTAL) return;
    if (idx < S0) { PB2_0[idx] = packB(l0_W2, HDIM, HDIM, KS1, idx); return; }
    idx -= S0;
    if (idx < S1) { PB2_1[idx] = packB(l1_W2, HDIM, HDIM, KS1, idx); return; }
    idx -= S1;
    if (idx < S2) { PB3_0[idx] = packB(l0_W3, HDIM, LDIM, KS2, idx); return; }
    idx -= S2;
    if (idx < S3) { PB3_1[idx] = packB(l1_W3, HDIM, LDIM, KS2, idx); return; }
    idx -= S3;
    if (idx < S4) { PW1[idx] = packProjW(l1_W1, LDIM, 4, idx); return; }
    idx -= S4;
    if (idx < S5) { PW0[idx] = packProjW(l0_W1, FDIM, 1, idx); return; }
    idx -= S5;
    if (idx < 320)       { b2p_0[idx] = (idx < HDIM) ? l0_b2[idx] : 0.f; return; }
    if (idx < 640)       { int n = idx - 320; b2p_1[n] = (n < HDIM) ? l1_b2[n] : 0.f; return; }
    if (idx < 1280)      { int n = idx - 640; bp1[n] = (n < HDIM) ? l1_b1[n] : 0.f; return; }
    if (idx < 1920)      { int n = idx - 1280; bp0[n] = (n < HDIM) ? l0_b1[n] : 0.f; return; }
    part[idx - 1920] = 0.f;          // re-zero pooled partials every launch
}

// ---------------------------------------------------------------------------
// proj GEMM: A[64 rows] x Weff[K,320-col group] -> UV fp16 (bias added, no relu).
// Grid = 800: block handles (row strip = bid>>1, group g = bid&1). 2 barriers.
// ---------------------------------------------------------------------------
template<int KS, bool A_IS_X>
__global__ __launch_bounds__(256) void proj_gemm_kernel(
    const void* __restrict__ Asrc, const unsigned short* __restrict__ PW,
    const float* __restrict__ bp,
    unsigned short* __restrict__ UV)
{
    __shared__ unsigned short As[4 * KS * 64 * 8];
    __shared__ unsigned short S[64 * SSTR];
    const int t = threadIdx.x;
    const int g = blockIdx.x & 1;
    const int row0 = (blockIdx.x >> 1) * 64;

    if constexpr (A_IS_X) {
        const float* x = (const float*)Asrc;
        int lane = t & 63, mt = t >> 6;
        int quad = lane >> 4;
        int grow = row0 + mt * 16 + (lane & 15);
        unsigned short oz[8];
#pragma unroll
        for (int j = 0; j < 8; ++j) {
            int k = quad * 8 + j;
            oz[j] = (k < FDIM) ? f2h(x[grow * FDIM + k]) : (unsigned short)0;
        }
        *(uint4*)(As + t * 8) = *(uint4*)oz;
    } else {
        const unsigned short* h = (const unsigned short*)Asrc;
#pragma unroll
        for (int i = 0; i < 4; ++i) {
            int s = t + 256 * i;
            int lane = s & 63;
            int ks = (s >> 6) % KS;
            int mt = s / (KS * 64);
            int grow = row0 + mt * 16 + (lane & 15);
            int k0 = ks * 32 + ((lane >> 4) << 3);
            *(uint4*)(As + s * 8) = *(const uint4*)(h + (size_t)grow * H0W + k0);
        }
    }
    __syncthreads();

    const int w = t >> 6, lane = t & 63, quad = lane >> 4, l15 = lane & 15;
    const int ntb = g * 20 + w * 5;

    floatx4 c[5][4];
#pragma unroll
    for (int i = 0; i < 5; ++i)
#pragma unroll
        for (int mt = 0; mt < 4; ++mt) c[i][mt] = (floatx4){0.f, 0.f, 0.f, 0.f};
#pragma unroll
    for (int ks = 0; ks < KS; ++ks) {
        half8 a[4];
#pragma unroll
        for (int mt = 0; mt < 4; ++mt)
            a[mt] = *(const half8*)(As + ((mt * KS + ks) * 64 + lane) * 8);
#pragma unroll
        for (int i = 0; i < 5; ++i) {
            half8 b = *(const half8*)(PW + (size_t)(((ntb + i) * KS + ks) * 64 + lane) * 8);
#pragma unroll
            for (int mt = 0; mt < 4; ++mt)
                c[i][mt] = __builtin_amdgcn_mfma_f32_16x16x32_f16(a[mt], b, c[i][mt], 0, 0, 0);
        }
    }
#pragma unroll
    for (int i = 0; i < 5; ++i) {
        int colp = (w * 5 + i) * 16 + l15;        // 0..319 group-local
        float bb = bp[g * 320 + colp];
#pragma unroll
        for (int mt = 0; mt < 4; ++mt) {
#pragma unroll
            for (int r = 0; r < 4; ++r) {
                int row = mt * 16 + quad * 4 + r;
                S[row * SSTR + colp] = f2h(c[i][mt][r] + bb);
            }
        }
    }
    __syncthreads();
#pragma unroll
    for (int it = 0; it < 10; ++it) {
        int s = t + 256 * it;
        int row = s / 40, c4 = s - row * 40;
        uint4 v = *(const uint4*)(S + row * SSTR + c4 * 8);
        *(uint4*)(UV + (size_t)(row0 + row) * UVW + g * 320 + c4 * 8) = v;
    }
}

// ---------------------------------------------------------------------------
// Fused edge MLP + segment-max. Block = 4 nodes (M=64), 512 threads / 8 waves.
// fp16 pipeline. Single 40 KB LDS buffer, 3 barriers.
//   GEMM1 (operand-swapped, mfma(W2^T-frag, Z1-frag)), BALANCED split:
//     40 half-tile units (tile B, mt-pair h); wave w owns units H=5w..5w+4,
//     H -> (B=H>>1, h=H&1); every wave issues exactly 100 MFMA (was 120/80).
//     Per ks: 3 PB2 frags (tiles (5w)>>1 ..+2) + 4 zb ds_reads, like before.
//     c1[j][m2][r] = H[n = B*16 + quad*4 + r][m = (2h+m2)*16 + l15]
//     -> packed fp16 epilogue, one ds_write_b64 per (unit, m2).
//   GEMM2: wave w<7 owns 1 ntile.
//   OUT_HALF=true : store h0 rows (fp16, padded to 128).
//   OUT_HALF=false: fused graph pooling -> atomicAdd / atomicMax into the
//     25-slices-per-graph part layout (32 contending blocks per address).
// ---------------------------------------------------------------------------
template<bool OUT_HALF>
__global__ __launch_bounds__(512, 4) void edge_mfma_kernel(
    const unsigned short* __restrict__ UV,
    const int* __restrict__ src,
    const unsigned short* __restrict__ PB2, const float* __restrict__ b2p,
    const unsigned short* __restrict__ PB3, const float* __restrict__ b3,
    void* __restrict__ hout)
{
    __shared__ unsigned short Zs[4 * KS1 * 64 * 8];   // 40960 B, Z1 then Z2

    const int t = threadIdx.x;
    const int node0 = blockIdx.x * 4;
    const int lane = t & 63;
    const int w = t >> 6;                 // 0..7
    const int quad = lane >> 4;
    const int l15 = lane & 15;
    const int slane = lane ^ ((lane & 0x30) >> 3);   // sigma(lane) for Z1 reads

    // Z1-build lane mapping (64B-coalesced gather + swizzled LDS dest)
    const int row16 = lane >> 2;          // 0..15
    const int part  = lane & 3;           // 0..3
    const int fl    = row16 + 16 * part;  // A-frag lane
    const int phys  = fl ^ (part << 1);   // sigma(fl)

    const half2v hzero = {(_Float16)0.f, (_Float16)0.f};

    // ---- Z1 build: 2560 slots, 5 per thread, packed fp16 math ----
#pragma unroll
    for (int i = 0; i < 5; ++i) {
        int s = t + 512 * i;
        int ks = (s >> 6) % KS1;
        int mt = s / (KS1 * 64);
        int m = mt * 16 + row16;
        int k0 = ks * 32 + part * 8;
        int srcn = src[node0 * 16 + m];
        UV4H ud, vd, o;
        ud.v = *(const uint4*)(UV + (size_t)(node0 + mt) * UVW + k0);
        vd.v = *(const uint4*)(UV + (size_t)srcn * UVW + HP + k0);
#pragma unroll
        for (int d = 0; d < 4; ++d) {
            half2v s2 = ud.h[d] + vd.h[d];                       // v_pk_add_f16
            o.h[d] = __builtin_elementwise_max(s2, hzero);       // v_pk_max_f16
        }
        *(uint4*)(Zs + ((mt * KS1 + ks) * 64 + phys) * 8) = o.v;
    }
    __syncthreads();

    // ---- GEMM1 (swapped, balanced): units H=5w..5w+4 -> (B=H>>1, h=H&1) ----
    const int B0 = (5 * w) >> 1;          // tiles touched: B0, B0+1, B0+2
    floatx4 c1[5][2];
#pragma unroll
    for (int j = 0; j < 5; ++j) {
        c1[j][0] = (floatx4){0.f, 0.f, 0.f, 0.f};
        c1[j][1] = (floatx4){0.f, 0.f, 0.f, 0.f};
    }
    const unsigned short* pb = PB2 + (size_t)B0 * (KS1 * 512) + lane * 8;

#define MM(A, B, C) __builtin_amdgcn_mfma_f32_16x16x32_f16((A), (B), (C), 0, 0, 0)
    if ((w & 1) == 0) {
        for (int ks = 0; ks < KS1; ++ks) {
            half8 zb[4];
#pragma unroll
            for (int mt = 0; mt < 4; ++mt)
                zb[mt] = *(const half8*)(Zs + ((mt * KS1 + ks) * 64 + slane) * 8);
            half8 wa0 = *(const half8*)(pb + (0 * KS1 + ks) * 512);
            half8 wa1 = *(const half8*)(pb + (1 * KS1 + ks) * 512);
            half8 wa2 = *(const half8*)(pb + (2 * KS1 + ks) * 512);
            c1[0][0] = MM(wa0, zb[0], c1[0][0]); c1[0][1] = MM(wa0, zb[1], c1[0][1]);
            c1[1][0] = MM(wa0, zb[2], c1[1][0]); c1[1][1] = MM(wa0, zb[3], c1[1][1]);
            c1[2][0] = MM(wa1, zb[0], c1[2][0]); c1[2][1] = MM(wa1, zb[1], c1[2][1]);
            c1[3][0] = MM(wa1, zb[2], c1[3][0]); c1[3][1] = MM(wa1, zb[3], c1[3][1]);
            c1[4][0] = MM(wa2, zb[0], c1[4][0]); c1[4][1] = MM(wa2, zb[1], c1[4][1]);
        }
    } else {
        for (int ks = 0; ks < KS1; ++ks) {
            half8 zb[4];
#pragma unroll
            for (int mt = 0; mt < 4; ++mt)
                zb[mt] = *(const half8*)(Zs + ((mt * KS1 + ks) * 64 + slane) * 8);
            half8 wa0 = *(const half8*)(pb + (0 * KS1 + ks) * 512);
            half8 wa1 = *(const half8*)(pb + (1 * KS1 + ks) * 512);
            half8 wa2 = *(const half8*)(pb + (2 * KS1 + ks) * 512);
            c1[0][0] = MM(wa0, zb[2], c1[0][0]); c1[0][1] = MM(wa0, zb[3], c1[0][1]);
            c1[1][0] = MM(wa1, zb[0], c1[1][0]); c1[1][1] = MM(wa1, zb[1], c1[1][1]);
            c1[2][0] = MM(wa1, zb[2], c1[2][0]); c1[2][1] = MM(wa1, zb[3], c1[2][1]);
            c1[3][0] = MM(wa2, zb[0], c1[3][0]); c1[3][1] = MM(wa2, zb[1], c1[3][1]);
            c1[4][0] = MM(wa2, zb[2], c1[4][0]); c1[4][1] = MM(wa2, zb[3], c1[4][1]);
        }
    }
#undef MM
    __syncthreads();   // all waves done reading Z1

    // ---- Z2 scatter (packed): unit (B,h) writes rows n=B*16+quad*4+{0..3},
    //      cols m=(2h+m2)*16+l15. Slot: ksq=B>>1, khi=(2B+(quad>>1))&3, jo=(quad&1)*4.
    auto z2u = [&](int j, int Bt, int h) {
        const floatx4 bb = *(const floatx4*)(b2p + Bt * 16 + quad * 4);
        half2v hb0 = pkrtz(bb[0], bb[1]);
        half2v hb1 = pkrtz(bb[2], bb[3]);
        int ksq = Bt >> 1;
        int khi = (2 * Bt + (quad >> 1)) & 3;
        int jo = (quad & 1) * 4;
#pragma unroll
        for (int m2 = 0; m2 < 2; ++m2) {
            int mt = 2 * h + m2;
            half2v c01 = pkrtz(c1[j][m2][0], c1[j][m2][1]);
            half2v c23 = pkrtz(c1[j][m2][2], c1[j][m2][3]);
            union { half2v hh[2]; unsigned long long ll; } o;
            o.hh[0] = __builtin_elementwise_max(c01 + hb0, hzero);
            o.hh[1] = __builtin_elementwise_max(c23 + hb1, hzero);
            *(unsigned long long*)(Zs + ((mt * KS1 + ksq) * 64 + l15 + 16 * khi) * 8 + jo) = o.ll;
        }
    };
    if ((w & 1) == 0) {
        z2u(0, B0, 0); z2u(1, B0, 1); z2u(2, B0 + 1, 0); z2u(3, B0 + 1, 1); z2u(4, B0 + 2, 0);
    } else {
        z2u(0, B0, 1); z2u(1, B0 + 1, 0); z2u(2, B0 + 1, 1); z2u(3, B0 + 2, 0); z2u(4, B0 + 2, 1);
    }
    __syncthreads();

    // ---- GEMM2: wave w<7 owns ntile w, all 4 mt ----
    floatx4 c2[4];
#pragma unroll
    for (int mt = 0; mt < 4; ++mt) c2[mt] = (floatx4){0.f, 0.f, 0.f, 0.f};
    if (w < NT2) {
        for (int ks = 0; ks < KS2; ++ks) {
            half8 a[4];
#pragma unroll
            for (int mt = 0; mt < 4; ++mt)
                a[mt] = *(const half8*)(Zs + ((mt * KS2 + ks) * 64 + lane) * 8);
            half8 b = *(const half8*)(PB3 + (size_t)((w * KS2 + ks) * 64 + lane) * 8);
#pragma unroll
            for (int mt = 0; mt < 4; ++mt)
                c2[mt] = __builtin_amdgcn_mfma_f32_16x16x32_f16(a[mt], b, c2[mt], 0, 0, 0);
        }
    }

    // ---- epilogue: max over 16 edge rows, +b3, relu ----
    if constexpr (OUT_HALF) {
#pragma unroll
        for (int mt = 0; mt < 4; ++mt) {
            int node = node0 + mt;
            if (w < NT2) {
                int col = w * 16 + l15;
                floatx4 a = c2[mt];
                float mx = fmaxf(fmaxf(a[0], a[1]), fmaxf(a[2], a[3]));
                mx = fmaxf(mx, __shfl_xor(mx, 16, 64));
                mx = fmaxf(mx, __shfl_xor(mx, 32, 64));
                if (quad == 0) {
                    unsigned short val = 0;
                    if (col < LDIM) val = f2h(fmaxf(mx + b3[col], 0.f));
                    ((unsigned short*)hout)[(size_t)node * H0W + col] = val;
                }
            }
            if (w == 7 && quad == 0)     // pad cols 112..127
                ((unsigned short*)hout)[(size_t)node * H0W + 112 + l15] = 0;
        }
    } else {
        // fused graph pooling into 25-slice partials
        if (w < NT2) {
            int col = w * 16 + l15;
            float bv = (col < LDIM) ? b3[col] : 0.f;
            float s4 = 0.f, m4 = 0.f;
#pragma unroll
            for (int mt = 0; mt < 4; ++mt) {
                floatx4 a = c2[mt];
                float mx = fmaxf(fmaxf(a[0], a[1]), fmaxf(a[2], a[3]));
                mx = fmaxf(mx, __shfl_xor(mx, 16, 64));
                mx = fmaxf(mx, __shfl_xor(mx, 32, 64));
                float v = fmaxf(mx + bv, 0.f);
                s4 += v;
                m4 = fmaxf(m4, v);
            }
            if (quad == 0 && col < LDIM) {
                int slice = blockIdx.x >> 5;          // = g*25 + sl  (32 blocks/slice)
                float* ps = (float*)hout + (size_t)slice * 200;
                atomicAdd(ps + col, s4);
                atomicMax((int*)(ps + 100 + col), __float_as_int(m4));
            }
        }
    }
}

// ---------------------------------------------------------------------------
__global__ __launch_bounds__(256) void final_kernel(
    const float* __restrict__ part,
    const float* __restrict__ W1, const float* __restrict__ b1,
    const float* __restrict__ W2, const float* __restrict__ b2,
    const float* __restrict__ W3, const float* __restrict__ b3,
    float* __restrict__ out)
{
    __shared__ float P[BGRAPHS][3 * LDIM];
    __shared__ float T1[BGRAPHS][LDIM];
    __shared__ float T2[BGRAPHS][LDIM];
    int t = threadIdx.x;
    for (int i = t; i < BGRAPHS * LDIM; i += 256) {
        int g = i / LDIM, f = i - (i / LDIM) * LDIM;
        float s = 0.f, mx = 0.f;
        for (int sl = 0; sl < 25; ++sl) {
            s += part[(size_t)(g * 25 + sl) * 200 + f];
            mx = fmaxf(mx, part[(size_t)(g * 25 + sl) * 200 + 100 + f]);
        }
        P[g][f] = s;
        P[g][LDIM + f] = s * (1.0f / NPG);
        P[g][2 * LDIM + f] = mx;
    }
    __syncthreads();
    for (int i = t; i < BGRAPHS * LDIM; i += 256) {
        int g = i / LDIM, c = i - (i / LDIM) * LDIM;
        float a = b1[c];
        for (int k = 0; k < 3 * LDIM; ++k) a = fmaf(P[g][k], W1[k * LDIM + c], a);
        T1[g][c] = fmaxf(a, 0.f);
    }
    __syncthreads();
    for (int i = t; i < BGRAPHS * LDIM; i += 256) {
        int g = i / LDIM, c = i - (i / LDIM) * LDIM;
        float a = b2[c];
        for (int k = 0; k < LDIM; ++k) a = fmaf(T1[g][k], W2[k * LDIM + c], a);
        T2[g][c] = fmaxf(a, 0.f);
    }
    __syncthreads();
    if (t < BGRAPHS) {
        float a = b3[0];
        for (int k = 0; k < LDIM; ++k) a = fmaf(T2[t][k], W3[k], a);
        out[t] = a;
    }
}

// ---------------------------------------------------------------------------
extern "C" void kernel_launch(void* const* d_in, const int* in_sizes, int n_in,
                              void* d_out, int out_size, void* d_ws, size_t ws_size,
                              hipStream_t stream)
{
    const float* x      = (const float*)d_in[0];
    const int*   src    = (const int*)d_in[1];
    const float* l0_W1  = (const float*)d_in[3];
    const float* l0_b1  = (const float*)d_in[4];
    const float* l0_W2  = (const float*)d_in[5];
    const float* l0_b2  = (const float*)d_in[6];
    const float* l0_W3  = (const float*)d_in[7];
    const float* l0_b3  = (const float*)d_in[8];
    const float* l1_W1  = (const float*)d_in[9];
    const float* l1_b1  = (const float*)d_in[10];
    const float* l1_W2  = (const float*)d_in[11];
    const float* l1_b2  = (const float*)d_in[12];
    const float* l1_W3  = (const float*)d_in[13];
    const float* l1_b3  = (const float*)d_in[14];
    const float* lin_W1 = (const float*)d_in[15];
    const float* lin_b1 = (const float*)d_in[16];
    const float* lin_W2 = (const float*)d_in[17];
    const float* lin_b2 = (const float*)d_in[18];
    const float* lin_W3 = (const float*)d_in[19];
    const float* lin_b3 = (const float*)d_in[20];
    float* out = (float*)d_out;

    char* p = (char*)d_ws;
    unsigned short* UV    = (unsigned short*)p;  p += (size_t)NNODES * UVW * 2;     // 32.77 MB
    unsigned short* h0b   = (unsigned short*)p;  p += (size_t)NNODES * H0W * 2;     // 6.55 MB
    unsigned short* PB2_0 = (unsigned short*)p;  p += (size_t)S0 * 2;
    unsigned short* PB2_1 = (unsigned short*)p;  p += (size_t)S1 * 2;
    unsigned short* PB3_0 = (unsigned short*)p;  p += (size_t)S2 * 2;
    unsigned short* PB3_1 = (unsigned short*)p;  p += (size_t)S3 * 2;
    unsigned short* PW1   = (unsigned short*)p;  p += (size_t)S4 * 2;
    unsigned short* PW0   = (unsigned short*)p;  p += (size_t)S5 * 2;
    float* b2p_0          = (float*)p;           p += HP * 4;
    float* b2p_1          = (float*)p;           p += HP * 4;
    float* bp1            = (float*)p;           p += 640 * 4;
    float* bp0            = (float*)p;           p += 640 * 4;
    float* part           = (float*)p;           p += (size_t)200 * 200 * 4;        // 25-slice partials

    pack_all_kernel<<<(PACK_TOTAL + 255) / 256, 256, 0, stream>>>(
        l0_W1, l0_b1, l0_W2, l0_b2, l0_W3,
        l1_W1, l1_b1, l1_W2, l1_b2, l1_W3,
        PB2_0, PB2_1, PB3_0, PB3_1, PW1, PW0, b2p_0, b2p_1, bp1, bp0, part);

    // layer 0
    proj_gemm_kernel<1, true><<<NNODES / 32, 256, 0, stream>>>(x, PW0, bp0, UV);
    edge_mfma_kernel<true><<<NNODES / 4, 512, 0, stream>>>(UV, src, PB2_0, b2p_0, PB3_0, l0_b3, h0b);
    // layer 1 (pooling fused via slice atomics into part)
    proj_gemm_kernel<4, false><<<NNODES / 32, 256, 0, stream>>>(h0b, PW1, bp1, UV);
    edge_mfma_kernel<false><<<NNODES / 4, 512, 0, stream>>>(UV, src, PB2_1, b2p_1, PB3_1, l1_b3, part);
    // head
    final_kernel<<<1, 256, 0, stream>>>(part, lin_W1, lin_b1, lin_W2, lin_b2, lin_W3, lin_b3, out);
}

// Round 7
// 410.513 us; speedup vs baseline: 1.0539x; 1.0539x over previous
//
#include <hip/hip_runtime.h>

#define NNODES 25600
#define DEG 16
#define BGRAPHS 8
#define NPG (NNODES / BGRAPHS)   // 3200
#define FDIM 7
#define HDIM 300
#define LDIM 100
#define HP 320                   // padded H
#define UVW 640                  // UV row width (U 0..319 | V 320..639)
#define NT1 20                   // GEMM1 N tiles
#define KS1 10                   // GEMM1 K steps
#define NT2 7                    // GEMM2 N tiles (112 cols, >=100 masked)
#define KS2 10                   // GEMM2 K steps
#define H0W 128                  // h0 fp16 padded width
#define SSTR 328                 // proj staging row stride (shorts)

typedef __attribute__((ext_vector_type(8))) _Float16 half8;
typedef __attribute__((ext_vector_type(2))) _Float16 half2v;
typedef __attribute__((ext_vector_type(4))) float floatx4;

__device__ __forceinline__ unsigned short f2h(float f) {   // fp32 -> fp16 bits (RNE)
    _Float16 h = (_Float16)f;
    return __builtin_bit_cast(unsigned short, h);
}

// packed fp32x2 -> fp16x2 (RTZ), re-typed to half2v
__device__ __forceinline__ half2v pkrtz(float a, float b) {
    return __builtin_bit_cast(half2v, __builtin_amdgcn_cvt_pkrtz(a, b));
}

union UV4H { uint4 v; half2v h[4]; };

// ---------------------------------------------------------------------------
// B-fragment packing: out[((nt*KS+ks)*64+lane)*8+j] = W[k][n]  (fp16 bits)
// ---------------------------------------------------------------------------
__device__ __forceinline__ unsigned short packB(const float* W, int Kreal, int Nreal,
                                                int KS, int rel)
{
    int j = rel & 7, lane = (rel >> 3) & 63, rem = rel >> 9;
    int ks = rem % KS, nt = rem / KS;
    int k = ks * 32 + ((lane >> 4) << 3) + j;
    int n = nt * 16 + (lane & 15);
    float v = (k < Kreal && n < Nreal) ? W[k * Nreal + n] : 0.f;
    return f2h(v);
}

// proj effective weights Weff[k][n], n<320 = U part (W1a - W1b), n>=320 = V part (W1b)
__device__ __forceinline__ unsigned short packProjW(const float* W1, int Ksub,
                                                    int KS, int rel)
{
    int j = rel & 7, lane = (rel >> 3) & 63, rem = rel >> 9;
    int ks = rem % KS, nt = rem / KS;
    int k = ks * 32 + ((lane >> 4) << 3) + j;
    int n = nt * 16 + (lane & 15);
    float v = 0.f;
    if (k < Ksub) {
        if (n < HP) { if (n < HDIM) v = W1[k * HDIM + n] - W1[(k + Ksub) * HDIM + n]; }
        else { int m = n - HP; if (m < HDIM) v = W1[(k + Ksub) * HDIM + m]; }
    }
    return f2h(v);
}

#define S0 102400   // PB2_0
#define S1 102400   // PB2_1
#define S2 35840    // PB3_0
#define S3 35840    // PB3_1
#define S4 81920    // PW1 (40 nt x 4 ks)
#define S5 20480    // PW0 (40 nt x 1 ks)
#define S6 1920     // biases
#define S7 40000    // part zero (200 slices x 200 floats)
#define PACK_TOTAL (S0+S1+S2+S3+S4+S5+S6+S7)

__global__ __launch_bounds__(256) void pack_all_kernel(
    const float* __restrict__ l0_W1, const float* __restrict__ l0_b1,
    const float* __restrict__ l0_W2, const float* __restrict__ l0_b2,
    const float* __restrict__ l0_W3,
    const float* __restrict__ l1_W1, const float* __restrict__ l1_b1,
    const float* __restrict__ l1_W2, const float* __restrict__ l1_b2,
    const float* __restrict__ l1_W3,
    unsigned short* __restrict__ PB2_0, unsigned short* __restrict__ PB2_1,
    unsigned short* __restrict__ PB3_0, unsigned short* __restrict__ PB3_1,
    unsigned short* __restrict__ PW1,  unsigned short* __restrict__ PW0,
    float* __restrict__ b2p_0, float* __restrict__ b2p_1,
    float* __restrict__ bp1,   float* __restrict__ bp0,
    float* __restrict__ part)
{
    int idx = blockIdx.x * 256 + threadIdx.x;
    if (idx >= PACK_TOTAL) return;
    if (idx < S0) { PB2_0[idx] = packB(l0_W2, HDIM, HDIM, KS1, idx); return; }
    idx -= S0;
    if (idx < S1) { PB2_1[idx] = packB(l1_W2, HDIM, HDIM, KS1, idx); return; }
    idx -= S1;
    if (idx < S2) { PB3_0[idx] = packB(l0_W3, HDIM, LDIM, KS2, idx); return; }
    idx -= S2;
    if (idx < S3) { PB3_1[idx] = packB(l1_W3, HDIM, LDIM, KS2, idx); return; }
    idx -= S3;
    if (idx < S4) { PW1[idx] = packProjW(l1_W1, LDIM, 4, idx); return; }
    idx -= S4;
    if (idx < S5) { PW0[idx] = packProjW(l0_W1, FDIM, 1, idx); return; }
    idx -= S5;
    if (idx < 320)       { b2p_0[idx] = (idx < HDIM) ? l0_b2[idx] : 0.f; return; }
    if (idx < 640)       { int n = idx - 320; b2p_1[n] = (n < HDIM) ? l1_b2[n] : 0.f; return; }
    if (idx < 1280)      { int n = idx - 640; bp1[n] = (n < HDIM) ? l1_b1[n] : 0.f; return; }
    if (idx < 1920)      { int n = idx - 1280; bp0[n] = (n < HDIM) ? l0_b1[n] : 0.f; return; }
    part[idx - 1920] = 0.f;          // re-zero pooled partials every launch
}

// ---------------------------------------------------------------------------
// proj GEMM: A[64 rows] x Weff[K,320-col group] -> UV fp16 (bias added, no relu).
// Grid = 800: block handles (row strip = bid>>1, group g = bid&1). 2 barriers.
// ---------------------------------------------------------------------------
template<int KS, bool A_IS_X>
__global__ __launch_bounds__(256) void proj_gemm_kernel(
    const void* __restrict__ Asrc, const unsigned short* __restrict__ PW,
    const float* __restrict__ bp,
    unsigned short* __restrict__ UV)
{
    __shared__ unsigned short As[4 * KS * 64 * 8];
    __shared__ unsigned short S[64 * SSTR];
    const int t = threadIdx.x;
    const int g = blockIdx.x & 1;
    const int row0 = (blockIdx.x >> 1) * 64;

    if constexpr (A_IS_X) {
        const float* x = (const float*)Asrc;
        int lane = t & 63, mt = t >> 6;
        int quad = lane >> 4;
        int grow = row0 + mt * 16 + (lane & 15);
        unsigned short oz[8];
#pragma unroll
        for (int j = 0; j < 8; ++j) {
            int k = quad * 8 + j;
            oz[j] = (k < FDIM) ? f2h(x[grow * FDIM + k]) : (unsigned short)0;
        }
        *(uint4*)(As + t * 8) = *(uint4*)oz;
    } else {
        const unsigned short* h = (const unsigned short*)Asrc;
#pragma unroll
        for (int i = 0; i < 4; ++i) {
            int s = t + 256 * i;
            int lane = s & 63;
            int ks = (s >> 6) % KS;
            int mt = s / (KS * 64);
            int grow = row0 + mt * 16 + (lane & 15);
            int k0 = ks * 32 + ((lane >> 4) << 3);
            *(uint4*)(As + s * 8) = *(const uint4*)(h + (size_t)grow * H0W + k0);
        }
    }
    __syncthreads();

    const int w = t >> 6, lane = t & 63, quad = lane >> 4, l15 = lane & 15;
    const int ntb = g * 20 + w * 5;

    floatx4 c[5][4];
#pragma unroll
    for (int i = 0; i < 5; ++i)
#pragma unroll
        for (int mt = 0; mt < 4; ++mt) c[i][mt] = (floatx4){0.f, 0.f, 0.f, 0.f};
#pragma unroll
    for (int ks = 0; ks < KS; ++ks) {
        half8 a[4];
#pragma unroll
        for (int mt = 0; mt < 4; ++mt)
            a[mt] = *(const half8*)(As + ((mt * KS + ks) * 64 + lane) * 8);
#pragma unroll
        for (int i = 0; i < 5; ++i) {
            half8 b = *(const half8*)(PW + (size_t)(((ntb + i) * KS + ks) * 64 + lane) * 8);
#pragma unroll
            for (int mt = 0; mt < 4; ++mt)
                c[i][mt] = __builtin_amdgcn_mfma_f32_16x16x32_f16(a[mt], b, c[i][mt], 0, 0, 0);
        }
    }
#pragma unroll
    for (int i = 0; i < 5; ++i) {
        int colp = (w * 5 + i) * 16 + l15;        // 0..319 group-local
        float bb = bp[g * 320 + colp];
#pragma unroll
        for (int mt = 0; mt < 4; ++mt) {
#pragma unroll
            for (int r = 0; r < 4; ++r) {
                int row = mt * 16 + quad * 4 + r;
                S[row * SSTR + colp] = f2h(c[i][mt][r] + bb);
            }
        }
    }
    __syncthreads();
#pragma unroll
    for (int it = 0; it < 10; ++it) {
        int s = t + 256 * it;
        int row = s / 40, c4 = s - row * 40;
        uint4 v = *(const uint4*)(S + row * SSTR + c4 * 8);
        *(uint4*)(UV + (size_t)(row0 + row) * UVW + g * 320 + c4 * 8) = v;
    }
}

// ---------------------------------------------------------------------------
// Fused edge MLP + segment-max. Block = 4 nodes (M=64), 512 threads / 8 waves.
// fp16 pipeline. Single 40 KB LDS buffer, 3 barriers. (r5 verified structure;
// r6's balanced split reverted - it spilled, WRITE 6.4->74 MB, VGPR 48->64.)
//   GEMM1 (operand-swapped, mfma(W2^T-frag, Z1-frag)), 20 tiles {3,3,3,3,2,2,2,2}:
//     c1[i][mt][r] = H[n = (base1+i)*16 + quad*4 + r][m = mt*16 + l15]
//     -> packed fp16 epilogue, one ds_write_b64 per (tile, mt).
//   GEMM2: wave w<7 owns 1 ntile.
//   OUT_HALF=true : store h0 rows (fp16, padded to 128).
//   OUT_HALF=false: fused graph pooling -> atomicAdd / atomicMax into the
//     25-slices-per-graph part layout (32 contending blocks per address;
//     relu outputs >= 0 so int-compare atomicMax is exact).
// ---------------------------------------------------------------------------
template<bool OUT_HALF>
__global__ __launch_bounds__(512, 4) void edge_mfma_kernel(
    const unsigned short* __restrict__ UV,
    const int* __restrict__ src,
    const unsigned short* __restrict__ PB2, const float* __restrict__ b2p,
    const unsigned short* __restrict__ PB3, const float* __restrict__ b3,
    void* __restrict__ hout)
{
    __shared__ unsigned short Zs[4 * KS1 * 64 * 8];   // 40960 B, Z1 then Z2

    const int t = threadIdx.x;
    const int node0 = blockIdx.x * 4;
    const int lane = t & 63;
    const int w = t >> 6;                 // 0..7
    const int quad = lane >> 4;
    const int l15 = lane & 15;
    const int slane = lane ^ ((lane & 0x30) >> 3);   // sigma(lane) for Z1 reads

    // Z1-build lane mapping (64B-coalesced gather + swizzled LDS dest)
    const int row16 = lane >> 2;          // 0..15
    const int part  = lane & 3;           // 0..3
    const int fl    = row16 + 16 * part;  // A-frag lane
    const int phys  = fl ^ (part << 1);   // sigma(fl)

    const half2v hzero = {(_Float16)0.f, (_Float16)0.f};

    // ---- Z1 build: 2560 slots, 5 per thread, packed fp16 math ----
#pragma unroll
    for (int i = 0; i < 5; ++i) {
        int s = t + 512 * i;
        int ks = (s >> 6) % KS1;
        int mt = s / (KS1 * 64);
        int m = mt * 16 + row16;
        int k0 = ks * 32 + part * 8;
        int srcn = src[node0 * 16 + m];
        UV4H ud, vd, o;
        ud.v = *(const uint4*)(UV + (size_t)(node0 + mt) * UVW + k0);
        vd.v = *(const uint4*)(UV + (size_t)srcn * UVW + HP + k0);
#pragma unroll
        for (int d = 0; d < 4; ++d) {
            half2v s2 = ud.h[d] + vd.h[d];                       // v_pk_add_f16
            o.h[d] = __builtin_elementwise_max(s2, hzero);       // v_pk_max_f16
        }
        *(uint4*)(Zs + ((mt * KS1 + ks) * 64 + phys) * 8) = o.v;
    }
    __syncthreads();

    // ---- GEMM1 (swapped): wave owns cnt1 ntiles starting at base1, all 4 mt ----
    const int cnt1  = (w < 4) ? 3 : 2;
    const int base1 = (w < 4) ? 3 * w : 12 + 2 * (w - 4);
    floatx4 c1[3][4];
#pragma unroll
    for (int i = 0; i < 3; ++i)
#pragma unroll
        for (int mt = 0; mt < 4; ++mt) c1[i][mt] = (floatx4){0.f, 0.f, 0.f, 0.f};
    for (int ks = 0; ks < KS1; ++ks) {
        half8 zb[4];
#pragma unroll
        for (int mt = 0; mt < 4; ++mt)
            zb[mt] = *(const half8*)(Zs + ((mt * KS1 + ks) * 64 + slane) * 8);
#pragma unroll
        for (int i = 0; i < 3; ++i) {
            if (i < cnt1) {
                half8 wa = *(const half8*)(PB2 + (size_t)(((base1 + i) * KS1 + ks) * 64 + lane) * 8);
#pragma unroll
                for (int mt = 0; mt < 4; ++mt)
                    c1[i][mt] = __builtin_amdgcn_mfma_f32_16x16x32_f16(wa, zb[mt], c1[i][mt], 0, 0, 0);
            }
        }
    }
    __syncthreads();   // all waves done reading Z1

    // ---- Z2 scatter (packed): lane holds rows n=B*16+quad*4+{0..3} of col m ----
    // Z2[m][n] -> A-frag slot: ks=n>>5, sub-lane hi=(n&31)>>3, j=n&7.
#pragma unroll
    for (int i = 0; i < 3; ++i) {
        if (i < cnt1) {
            int B = base1 + i;                       // ntile 0..19
            const floatx4 bb = *(const floatx4*)(b2p + B * 16 + quad * 4);
            half2v hb0 = pkrtz(bb[0], bb[1]);
            half2v hb1 = pkrtz(bb[2], bb[3]);
            int ks = B >> 1;
            int khi = (2 * B + (quad >> 1)) & 3;
            int jo = (quad & 1) * 4;
#pragma unroll
            for (int mt = 0; mt < 4; ++mt) {
                half2v c01 = pkrtz(c1[i][mt][0], c1[i][mt][1]);
                half2v c23 = pkrtz(c1[i][mt][2], c1[i][mt][3]);
                union { half2v h[2]; unsigned long long ll; } o;
                o.h[0] = __builtin_elementwise_max(c01 + hb0, hzero);
                o.h[1] = __builtin_elementwise_max(c23 + hb1, hzero);
                *(unsigned long long*)(Zs + ((mt * KS1 + ks) * 64 + l15 + 16 * khi) * 8 + jo) = o.ll;
            }
        }
    }
    __syncthreads();

    // ---- GEMM2: wave w<7 owns ntile w, all 4 mt ----
    floatx4 c2[4];
#pragma unroll
    for (int mt = 0; mt < 4; ++mt) c2[mt] = (floatx4){0.f, 0.f, 0.f, 0.f};
    if (w < NT2) {
        for (int ks = 0; ks < KS2; ++ks) {
            half8 a[4];
#pragma unroll
            for (int mt = 0; mt < 4; ++mt)
                a[mt] = *(const half8*)(Zs + ((mt * KS2 + ks) * 64 + lane) * 8);
            half8 b = *(const half8*)(PB3 + (size_t)((w * KS2 + ks) * 64 + lane) * 8);
#pragma unroll
            for (int mt = 0; mt < 4; ++mt)
                c2[mt] = __builtin_amdgcn_mfma_f32_16x16x32_f16(a[mt], b, c2[mt], 0, 0, 0);
        }
    }

    // ---- epilogue: max over 16 edge rows, +b3, relu ----
    if constexpr (OUT_HALF) {
#pragma unroll
        for (int mt = 0; mt < 4; ++mt) {
            int node = node0 + mt;
            if (w < NT2) {
                int col = w * 16 + l15;
                floatx4 a = c2[mt];
                float mx = fmaxf(fmaxf(a[0], a[1]), fmaxf(a[2], a[3]));
                mx = fmaxf(mx, __shfl_xor(mx, 16, 64));
                mx = fmaxf(mx, __shfl_xor(mx, 32, 64));
                if (quad == 0) {
                    unsigned short val = 0;
                    if (col < LDIM) val = f2h(fmaxf(mx + b3[col], 0.f));
                    ((unsigned short*)hout)[(size_t)node * H0W + col] = val;
                }
            }
            if (w == 7 && quad == 0)     // pad cols 112..127
                ((unsigned short*)hout)[(size_t)node * H0W + 112 + l15] = 0;
        }
    } else {
        // fused graph pooling into 25-slice partials
        if (w < NT2) {
            int col = w * 16 + l15;
            float bv = (col < LDIM) ? b3[col] : 0.f;
            float s4 = 0.f, m4 = 0.f;
#pragma unroll
            for (int mt = 0; mt < 4; ++mt) {
                floatx4 a = c2[mt];
                float mx = fmaxf(fmaxf(a[0], a[1]), fmaxf(a[2], a[3]));
                mx = fmaxf(mx, __shfl_xor(mx, 16, 64));
                mx = fmaxf(mx, __shfl_xor(mx, 32, 64));
                float v = fmaxf(mx + bv, 0.f);
                s4 += v;
                m4 = fmaxf(m4, v);
            }
            if (quad == 0 && col < LDIM) {
                int slice = blockIdx.x >> 5;          // = g*25 + sl  (32 blocks/slice)
                float* ps = (float*)hout + (size_t)slice * 200;
                atomicAdd(ps + col, s4);
                atomicMax((int*)(ps + 100 + col), __float_as_int(m4));
            }
        }
    }
}

// ---------------------------------------------------------------------------
__global__ __launch_bounds__(256) void final_kernel(
    const float* __restrict__ part,
    const float* __restrict__ W1, const float* __restrict__ b1,
    const float* __restrict__ W2, const float* __restrict__ b2,
    const float* __restrict__ W3, const float* __restrict__ b3,
    float* __restrict__ out)
{
    __shared__ float P[BGRAPHS][3 * LDIM];
    __shared__ float T1[BGRAPHS][LDIM];
    __shared__ float T2[BGRAPHS][LDIM];
    int t = threadIdx.x;
    for (int i = t; i < BGRAPHS * LDIM; i += 256) {
        int g = i / LDIM, f = i - (i / LDIM) * LDIM;
        float s = 0.f, mx = 0.f;
        for (int sl = 0; sl < 25; ++sl) {
            s += part[(size_t)(g * 25 + sl) * 200 + f];
            mx = fmaxf(mx, part[(size_t)(g * 25 + sl) * 200 + 100 + f]);
        }
        P[g][f] = s;
        P[g][LDIM + f] = s * (1.0f / NPG);
        P[g][2 * LDIM + f] = mx;
    }
    __syncthreads();
    for (int i = t; i < BGRAPHS * LDIM; i += 256) {
        int g = i / LDIM, c = i - (i / LDIM) * LDIM;
        float a = b1[c];
        for (int k = 0; k < 3 * LDIM; ++k) a = fmaf(P[g][k], W1[k * LDIM + c], a);
        T1[g][c] = fmaxf(a, 0.f);
    }
    __syncthreads();
    for (int i = t; i < BGRAPHS * LDIM; i += 256) {
        int g = i / LDIM, c = i - (i / LDIM) * LDIM;
        float a = b2[c];
        for (int k = 0; k < LDIM; ++k) a = fmaf(T1[g][k], W2[k * LDIM + c], a);
        T2[g][c] = fmaxf(a, 0.f);
    }
    __syncthreads();
    if (t < BGRAPHS) {
        float a = b3[0];
        for (int k = 0; k < LDIM; ++k) a = fmaf(T2[t][k], W3[k], a);
        out[t] = a;
    }
}

// ---------------------------------------------------------------------------
extern "C" void kernel_launch(void* const* d_in, const int* in_sizes, int n_in,
                              void* d_out, int out_size, void* d_ws, size_t ws_size,
                              hipStream_t stream)
{
    const float* x      = (const float*)d_in[0];
    const int*   src    = (const int*)d_in[1];
    const float* l0_W1  = (const float*)d_in[3];
    const float* l0_b1  = (const float*)d_in[4];
    const float* l0_W2  = (const float*)d_in[5];
    const float* l0_b2  = (const float*)d_in[6];
    const float* l0_W3  = (const float*)d_in[7];
    const float* l0_b3  = (const float*)d_in[8];
    const float* l1_W1  = (const float*)d_in[9];
    const float* l1_b1  = (const float*)d_in[10];
    const float* l1_W2  = (const float*)d_in[11];
    const float* l1_b2  = (const float*)d_in[12];
    const float* l1_W3  = (const float*)d_in[13];
    const float* l1_b3  = (const float*)d_in[14];
    const float* lin_W1 = (const float*)d_in[15];
    const float* lin_b1 = (const float*)d_in[16];
    const float* lin_W2 = (const float*)d_in[17];
    const float* lin_b2 = (const float*)d_in[18];
    const float* lin_W3 = (const float*)d_in[19];
    const float* lin_b3 = (const float*)d_in[20];
    float* out = (float*)d_out;

    char* p = (char*)d_ws;
    unsigned short* UV    = (unsigned short*)p;  p += (size_t)NNODES * UVW * 2;     // 32.77 MB
    unsigned short* h0b   = (unsigned short*)p;  p += (size_t)NNODES * H0W * 2;     // 6.55 MB
    unsigned short* PB2_0 = (unsigned short*)p;  p += (size_t)S0 * 2;
    unsigned short* PB2_1 = (unsigned short*)p;  p += (size_t)S1 * 2;
    unsigned short* PB3_0 = (unsigned short*)p;  p += (size_t)S2 * 2;
    unsigned short* PB3_1 = (unsigned short*)p;  p += (size_t)S3 * 2;
    unsigned short* PW1   = (unsigned short*)p;  p += (size_t)S4 * 2;
    unsigned short* PW0   = (unsigned short*)p;  p += (size_t)S5 * 2;
    float* b2p_0          = (float*)p;           p += HP * 4;
    float* b2p_1          = (float*)p;           p += HP * 4;
    float* bp1            = (float*)p;           p += 640 * 4;
    float* bp0            = (float*)p;           p += 640 * 4;
    float* part           = (float*)p;           p += (size_t)200 * 200 * 4;        // 25-slice partials

    pack_all_kernel<<<(PACK_TOTAL + 255) / 256, 256, 0, stream>>>(
        l0_W1, l0_b1, l0_W2, l0_b2, l0_W3,
        l1_W1, l1_b1, l1_W2, l1_b2, l1_W3,
        PB2_0, PB2_1, PB3_0, PB3_1, PW1, PW0, b2p_0, b2p_1, bp1, bp0, part);

    // layer 0
    proj_gemm_kernel<1, true><<<NNODES / 32, 256, 0, stream>>>(x, PW0, bp0, UV);
    edge_mfma_kernel<true><<<NNODES / 4, 512, 0, stream>>>(UV, src, PB2_0, b2p_0, PB3_0, l0_b3, h0b);
    // layer 1 (pooling fused via slice atomics into part)
    proj_gemm_kernel<4, false><<<NNODES / 32, 256, 0, stream>>>(h0b, PW1, bp1, UV);
    edge_mfma_kernel<false><<<NNODES / 4, 512, 0, stream>>>(UV, src, PB2_1, b2p_1, PB3_1, l1_b3, part);
    // head
    final_kernel<<<1, 256, 0, stream>>>(part, lin_W1, lin_b1, lin_W2, lin_b2, lin_W3, lin_b3, out);
}